// Round 9
// baseline (164.557 us; speedup 1.0000x reference)
//
#include <hip/hip_runtime.h>

// FixedSparseMultiHead: B=2, S=2048, D=1024, H=16, Hd=64, local band ±102.
// Round 9: TLP-first GEMM. 128x64 tiles, 2-wave (128-thr) blocks, 24KB LDS
//   -> QKV grid 1536 = exactly 6 blocks/CU (12 waves/CU, was ~5).
//   Per-wave mix unchanged (16 MFMA + 8 ds_read/step, conflict-free chunks).
//   Simple verified schedule: stage(next); read(cur); MFMA; __syncthreads.
// Everything else = round 7/8 (fp16 single-product GEMMs, bf16 attention).
// Fallback fp32 path if ws_size < 80MB.

#define SEQ    2048
#define DMODEL 1024
#define NHEAD  16
#define HDIM   64
#define HALFW  102
#define BWMAX  240
#define VTS    2176    // padded V^T row stride (zeros beyond SEQ)

typedef unsigned short u16;
typedef __attribute__((ext_vector_type(8))) short bf16x8;
typedef __attribute__((ext_vector_type(8))) _Float16 f16x8;
typedef __attribute__((ext_vector_type(4))) float f32x4;

__device__ __forceinline__ u16 f2bf(float f) {
    unsigned u = __builtin_bit_cast(unsigned, f);
    unsigned r = (u + 0x7fffu + ((u >> 16) & 1u)) >> 16;   // RNE
    return (u16)r;
}
__device__ __forceinline__ float bf2f(u16 u) {
    return __builtin_bit_cast(float, ((unsigned)u) << 16);
}
__device__ __forceinline__ u16 f2h(float f) {
    return __builtin_bit_cast(u16, (_Float16)f);           // RNE
}

__device__ __forceinline__ void gload16(const void* g, void* l) {
    __builtin_amdgcn_global_load_lds(
        (const __attribute__((address_space(1))) void*)g,
        (__attribute__((address_space(3))) void*)l, 16, 0, 0);
}

// ---------------------------------------------------------------------------
// split: fp32 -> fp16.  y=0: x (4M elems); y=1..4: Wq/Wk/Wv/Wo (1M each).
// ---------------------------------------------------------------------------
__global__ __launch_bounds__(256) void split5(
    const float* __restrict__ x,  const float* __restrict__ wq,
    const float* __restrict__ wk, const float* __restrict__ wv,
    const float* __restrict__ wo,
    u16* __restrict__ xh, u16* __restrict__ wbase)
{
    const int y = blockIdx.y;
    const float* src; u16* dst; int nblk;
    switch (y) {
      case 0:  src = x;  dst = xh;              nblk = 4096; break;
      case 1:  src = wq; dst = wbase;           nblk = 1024; break;
      case 2:  src = wk; dst = wbase + 1048576; nblk = 1024; break;
      case 3:  src = wv; dst = wbase + 2097152; nblk = 1024; break;
      default: src = wo; dst = wbase + 3145728; nblk = 1024; break;
    }
    const int bx = blockIdx.x;
    if (bx >= nblk) return;
    const int i = (bx * 256 + threadIdx.x) * 4;
    const float4 v = *(const float4*)(src + i);
    ushort4 h;
    h.x = f2h(v.x); h.y = f2h(v.y); h.z = f2h(v.z); h.w = f2h(v.w);
    *(ushort4*)(dst + i) = h;
}

// ---------------------------------------------------------------------------
// MFMA GEMM core, fp16: C[128x64] = A*B^T, K=1024, BK=32, 32 steps.
// 128 thr = 2 waves; wave w owns rows m0+w*64..+63, all 64 cols.
// LDS: sA 2 buf x 8 chunks, sB 2 buf x 4 chunks; chunk = [4kh][16row][8elem]
//   = 1KB, lane-linear (gload_lds dst = chunk + ln*16B; ds_read_b128 at the
//   same address) -> conflict-free (verified r5-r8). 24 KB total -> 6 blk/CU.
// Staging per step: wave w loads A chunks w*4..w*4+3, B chunks w*2..w*2+1
//   (6 gload16/wave). Schedule: stage(next); read(cur); 16 MFMA; syncthreads.
// ---------------------------------------------------------------------------
__device__ __forceinline__ void gemm_core(
    const u16* __restrict__ A, const u16* __restrict__ B,
    int m0, int n0, u16 (*sA)[4096], u16 (*sB)[2048], f32x4 acc[4][4])
{
    const int tid = threadIdx.x, ln = tid & 63, w = tid >> 6;
    const int srow = ln & 15, scol = (ln >> 4) * 8;

#pragma unroll
    for (int fm = 0; fm < 4; ++fm)
#pragma unroll
        for (int fn = 0; fn < 4; ++fn) acc[fm][fn] = (f32x4){0.f, 0.f, 0.f, 0.f};

    auto stage = [&](int buf, int k0) {
#pragma unroll
        for (int c = 0; c < 4; ++c)
            gload16(A + (size_t)(m0 + (w * 4 + c) * 16 + srow) * 1024 + k0 + scol,
                    sA[buf] + (w * 4 + c) * 512);
#pragma unroll
        for (int c = 0; c < 2; ++c)
            gload16(B + (size_t)(n0 + (w * 2 + c) * 16 + srow) * 1024 + k0 + scol,
                    sB[buf] + (w * 2 + c) * 512);
    };

    stage(0, 0);
    __syncthreads();

    for (int t = 0; t < 32; ++t) {
        const int cur = t & 1;
        if (t + 1 < 32) stage(cur ^ 1, (t + 1) << 5);

        f16x8 a[4], b[4];
#pragma unroll
        for (int f = 0; f < 4; ++f) {
            a[f] = *(const f16x8*)(sA[cur] + (w * 4 + f) * 512 + ln * 8);
            b[f] = *(const f16x8*)(sB[cur] + f * 512 + ln * 8);
        }
#pragma unroll
        for (int fm = 0; fm < 4; ++fm)
#pragma unroll
            for (int fn = 0; fn < 4; ++fn)
                acc[fm][fn] = __builtin_amdgcn_mfma_f32_16x16x32_f16(
                    a[fm], b[fn], acc[fm][fn], 0, 0, 0);
        __syncthreads();
    }
}

// ---------------------------------------------------------------------------
// Fused Q/K/V^T projection, 512 blocks/y, 128 threads.
// y=0: Q bf16 [B,H,S,64]; y=1: K bf16; y=2: V^T bf16 [B,H,64,VTS] (A=Wv, B=x).
// ---------------------------------------------------------------------------
__global__ __launch_bounds__(128) void gemm_qkv(
    const u16* __restrict__ xh, const u16* __restrict__ wbase,
    const float* __restrict__ bq, const float* __restrict__ bk,
    const float* __restrict__ bvv,
    u16* __restrict__ Qo, u16* __restrict__ Ko, u16* __restrict__ VTo)
{
    __shared__ u16 sA[2][4096], sB[2][2048];   // 24 KB
    const int y = blockIdx.y;
    const u16* W = wbase + (size_t)y * 1048576;

    const int bx = blockIdx.x;
    int m0, n0;
    if (y == 2) {
        // M=1024 (d), N=4096 (s): mt = bx&7 (XCD-pinned), nt = bx>>3
        m0 = (bx & 7) * 128; n0 = (bx >> 3) * 64;
    } else {
        // M=4096, N=1024: XCD x owns m-tiles x*4..x*4+3, all 16 n-tiles
        m0 = ((bx & 7) * 4 + ((bx >> 3) & 3)) * 128;
        n0 = (bx >> 5) * 64;
    }

    f32x4 acc[4][4];
    if (y == 2) gemm_core(W, xh, m0, n0, sA, sB, acc);
    else        gemm_core(xh, W, m0, n0, sA, sB, acc);

    const int tid = threadIdx.x, ln = tid & 63, w = tid >> 6;
    const int rl = ln & 15, kh = ln >> 4;

    if (y == 2) {
        // C[m=d-row][n=s-col] -> VT[(b*16+h)*64+hd][s], row stride VTS
#pragma unroll
        for (int fn = 0; fn < 4; ++fn) {
            const int n  = n0 + fn * 16 + rl;             // 0..4095 (s)
            const int bb = n >> 11, s = n & (SEQ - 1);
#pragma unroll
            for (int fm = 0; fm < 4; ++fm)
#pragma unroll
                for (int r = 0; r < 4; ++r) {
                    const int m = m0 + w * 64 + fm * 16 + kh * 4 + r;   // 0..1023 (d)
                    const float o = acc[fm][fn][r] + bvv[m];
                    const int row = (bb * NHEAD + (m >> 6)) * HDIM + (m & 63);
                    VTo[(size_t)row * VTS + s] = f2bf(o);
                }
        }
    } else {
        const float* bias = (y == 0) ? bq : bk;
        u16* Y = (y == 0) ? Qo : Ko;
#pragma unroll
        for (int fn = 0; fn < 4; ++fn) {
            const int n = n0 + fn * 16 + rl;
            const float bb = bias[n];
            const int h = n >> 6, hd = n & 63;
#pragma unroll
            for (int fm = 0; fm < 4; ++fm)
#pragma unroll
                for (int r = 0; r < 4; ++r) {
                    const int m = m0 + w * 64 + fm * 16 + kh * 4 + r;
                    const int b = m >> 11, s = m & (SEQ - 1);
                    Y[((size_t)(b * NHEAD + h) * SEQ + s) * HDIM + hd] =
                        f2bf(acc[fm][fn][r] + bb);
                }
        }
    }
}

// Final projection: out = AO@Wo^T + bo, fp32 out. 512 blocks, 128 threads.
__global__ __launch_bounds__(128) void gemm_out(
    const u16* __restrict__ A, const u16* __restrict__ B,
    const float* __restrict__ bias, float* __restrict__ Y)
{
    __shared__ u16 sA[2][4096], sB[2][2048];   // 24 KB
    const int bx = blockIdx.x;
    const int m0 = ((bx & 7) * 4 + ((bx >> 3) & 3)) * 128;
    const int n0 = (bx >> 5) * 64;

    f32x4 acc[4][4];
    gemm_core(A, B, m0, n0, sA, sB, acc);

    const int tid = threadIdx.x, ln = tid & 63, w = tid >> 6;
    const int rl = ln & 15, kh = ln >> 4;
#pragma unroll
    for (int fn = 0; fn < 4; ++fn) {
        const int n = n0 + fn * 16 + rl;
        const float bb = bias[n];
#pragma unroll
        for (int fm = 0; fm < 4; ++fm)
#pragma unroll
            for (int r = 0; r < 4; ++r) {
                const int m = m0 + w * 64 + fm * 16 + kh * 4 + r;
                Y[(size_t)m * DMODEL + n] = acc[fm][fn][r] + bb;
            }
    }
}

// ---------------------------------------------------------------------------
// MFMA banded attention (r4-verified structure). Epilogue writes AO fp16.
// ---------------------------------------------------------------------------
__global__ __launch_bounds__(256) void attn_mfma(
    const u16* __restrict__ Q, const u16* __restrict__ K,
    const u16* __restrict__ VT, u16* __restrict__ aoh)
{
    __shared__ u16 P_lds[4][16][232];   // 232-elem stride: 2-way banks (free)

    const int tid = threadIdx.x, ln = tid & 63, wv = tid >> 6;
    const int bx0 = blockIdx.x;
    const int asg = (bx0 & 7) * 128 + (bx0 >> 3);   // 1024 = 8 XCD * 128
    const int bh  = asg >> 5;
    const int qt  = asg & 31;
    const int b   = bh >> 4, h = bh & 15;
    const int q0  = qt * 64 + wv * 16;
    const int jmin = (q0 >= 104) ? (q0 - 104) : 0;   // == 0 (mod 8)

    const u16* Qbh  = Q  + (size_t)bh * SEQ * HDIM;
    const u16* Kbh  = K  + (size_t)bh * SEQ * HDIM;
    const u16* VTbh = VT + (size_t)bh * HDIM * VTS;

    const int lr = ln & 15, lk = ln >> 4;

    const bf16x8 qf0 = *(const bf16x8*)(Qbh + (size_t)(q0 + lr) * HDIM + lk * 8);
    const bf16x8 qf1 = *(const bf16x8*)(Qbh + (size_t)(q0 + lr) * HDIM + 32 + lk * 8);

    // ---- QK^T: 14 tiles x 2 MFMA ----
    f32x4 sc[14];
#pragma unroll
    for (int t = 0; t < 14; ++t) {
        const int j  = jmin + t * 16 + lr;
        const int jc = min(j, SEQ - 1);          // clamped load; masked below
        const u16* kp = Kbh + (size_t)jc * HDIM + lk * 8;
        const bf16x8 k0 = *(const bf16x8*)kp;
        const bf16x8 k1 = *(const bf16x8*)(kp + 32);
        f32x4 a = (f32x4){0.f, 0.f, 0.f, 0.f};
        a = __builtin_amdgcn_mfma_f32_16x16x32_bf16(qf0, k0, a, 0, 0, 0);
        a = __builtin_amdgcn_mfma_f32_16x16x32_bf16(qf1, k1, a, 0, 0, 0);
        sc[t] = a;
    }

    // ---- masked softmax, per C-row r (16-lane group shares a row) ----
    float lrow[4];
#pragma unroll
    for (int r = 0; r < 4; ++r) {
        const int i = q0 + lk * 4 + r;
        float mx = -3.0e38f;
#pragma unroll
        for (int t = 0; t < 14; ++t) {
            const int j = jmin + t * 16 + lr;
            float v = sc[t][r] * 0.125f;
            const bool ok = (j >= i - HALFW) && (j <= i + HALFW) && (j < SEQ);
            v = ok ? v : -3.0e38f;
            sc[t][r] = v;
            mx = fmaxf(mx, v);
        }
#pragma unroll
        for (int off = 8; off > 0; off >>= 1) mx = fmaxf(mx, __shfl_xor(mx, off));
        float sum = 0.f;
#pragma unroll
        for (int t = 0; t < 14; ++t) {
            const float p = __expf(sc[t][r] - mx);   // masked -> exactly 0
            sum += p;
            P_lds[wv][lk * 4 + r][t * 16 + lr] = f2bf(p);
        }
#pragma unroll
        for (int off = 8; off > 0; off >>= 1) sum += __shfl_xor(sum, off);
        lrow[r] = sum;
    }
    // same-wave LDS write->read; compiler inserts lgkmcnt waits

    // ---- PV: 7 k-chunks x 4 d-tiles, aligned unclamped V^T loads ----
    f32x4 ao[4];
#pragma unroll
    for (int nt = 0; nt < 4; ++nt) ao[nt] = (f32x4){0.f, 0.f, 0.f, 0.f};
#pragma unroll
    for (int kc = 0; kc < 7; ++kc) {
        const bf16x8 pf = *(const bf16x8*)&P_lds[wv][lr][kc * 32 + lk * 8];
        const int jb = jmin + kc * 32 + lk * 8;   // 16B aligned, < VTS
#pragma unroll
        for (int nt = 0; nt < 4; ++nt) {
            const bf16x8 vf = *(const bf16x8*)(VTbh + (size_t)(nt * 16 + lr) * VTS + jb);
            ao[nt] = __builtin_amdgcn_mfma_f32_16x16x32_bf16(pf, vf, ao[nt], 0, 0, 0);
        }
    }

    // ---- epilogue: AO -> fp16 [4096][1024] ----
#pragma unroll
    for (int nt = 0; nt < 4; ++nt)
#pragma unroll
        for (int r = 0; r < 4; ++r) {
            const int i = q0 + lk * 4 + r;
            const float o = ao[nt][r] / lrow[r];
            aoh[((size_t)b * SEQ + i) * DMODEL + h * HDIM + nt * 16 + lr] = f2h(o);
        }
}

// ---------------------------------------------------------------------------
// Round-1 fp32 path (fallback only).
// ---------------------------------------------------------------------------
template<int QKV>
__global__ __launch_bounds__(256) void gemm_xwt(
    const float* __restrict__ X, const float* __restrict__ W,
    const float* __restrict__ bias, float* __restrict__ Y)
{
    __shared__ float As[16][132];
    __shared__ float Bs[16][68];
    const int tid = threadIdx.x;
    const int bx  = blockIdx.x;
    const int n0  = (bx & 15) * 64;
    const int m0  = (bx >> 4) * 128;
    const int ty  = tid >> 4, tx = tid & 15;
    float acc[8][4];
#pragma unroll
    for (int r = 0; r < 8; ++r)
#pragma unroll
        for (int c = 0; c < 4; ++c) acc[r][c] = 0.f;
    const int lrow = tid >> 2, lkq = (tid & 3) * 4;
    for (int k0 = 0; k0 < DMODEL; k0 += 16) {
        float4 a0 = *(const float4*)(X + (size_t)(m0 + lrow)      * DMODEL + k0 + lkq);
        float4 a1 = *(const float4*)(X + (size_t)(m0 + lrow + 64) * DMODEL + k0 + lkq);
        float4 b0 = *(const float4*)(W + (size_t)(n0 + lrow)      * DMODEL + k0 + lkq);
        __syncthreads();
        As[lkq + 0][lrow] = a0.x; As[lkq + 1][lrow] = a0.y;
        As[lkq + 2][lrow] = a0.z; As[lkq + 3][lrow] = a0.w;
        As[lkq + 0][lrow + 64] = a1.x; As[lkq + 1][lrow + 64] = a1.y;
        As[lkq + 2][lrow + 64] = a1.z; As[lkq + 3][lrow + 64] = a1.w;
        Bs[lkq + 0][lrow] = b0.x; Bs[lkq + 1][lrow] = b0.y;
        Bs[lkq + 2][lrow] = b0.z; Bs[lkq + 3][lrow] = b0.w;
        __syncthreads();
#pragma unroll
        for (int k = 0; k < 16; ++k) {
            float4 av0 = *(const float4*)&As[k][ty * 8];
            float4 av1 = *(const float4*)&As[k][ty * 8 + 4];
            float4 bv  = *(const float4*)&Bs[k][tx * 4];
            float a[8] = {av0.x, av0.y, av0.z, av0.w, av1.x, av1.y, av1.z, av1.w};
            float bb[4] = {bv.x, bv.y, bv.z, bv.w};
#pragma unroll
            for (int r = 0; r < 8; ++r)
#pragma unroll
                for (int c = 0; c < 4; ++c) acc[r][c] += a[r] * bb[c];
        }
    }
    const float4 bb = *(const float4*)(bias + n0 + tx * 4);
    if (QKV) {
        const int b = m0 >> 11, h = n0 >> 6;
#pragma unroll
        for (int r = 0; r < 8; ++r) {
            const int m = m0 + ty * 8 + r, ss = m & (SEQ - 1);
            float4 o = {acc[r][0] + bb.x, acc[r][1] + bb.y, acc[r][2] + bb.z, acc[r][3] + bb.w};
            *(float4*)(Y + ((size_t)(b * NHEAD + h) * SEQ + ss) * HDIM + tx * 4) = o;
        }
    } else {
#pragma unroll
        for (int r = 0; r < 8; ++r) {
            const int m = m0 + ty * 8 + r;
            float4 o = {acc[r][0] + bb.x, acc[r][1] + bb.y, acc[r][2] + bb.z, acc[r][3] + bb.w};
            *(float4*)(Y + (size_t)m * DMODEL + n0 + tx * 4) = o;
        }
    }
}

__global__ __launch_bounds__(256) void attn_local_f32(
    const float* __restrict__ Q, const float* __restrict__ K,
    const float* __restrict__ V, float* __restrict__ O)
{
    __shared__ float ssc[32][BWMAX];
    const int tid = threadIdx.x;
    const int bx0 = blockIdx.x;
    const int bx  = (bx0 & 7) * 256 + (bx0 >> 3);
    const int qt  = bx & 63;
    const int h   = (bx >> 6) & 15;
    const int b   = bx >> 10;
    const int i0  = qt * 32;
    const int jmin = max(0, i0 - HALFW);
    const int jmax = min(SEQ - 1, i0 + 31 + HALFW);
    const int BWt  = jmax - jmin + 1;
    const float* Qbh = Q + (size_t)(b * NHEAD + h) * SEQ * HDIM;
    const float* Kbh = K + (size_t)(b * NHEAD + h) * SEQ * HDIM;
    const float* Vbh = V + (size_t)(b * NHEAD + h) * SEQ * HDIM;
    const int jj = tid;
    if (jj < BWt) {
        float acc[32];
#pragma unroll
        for (int i = 0; i < 32; ++i) acc[i] = 0.f;
        const float* kp = Kbh + (size_t)(jmin + jj) * HDIM;
        for (int d0 = 0; d0 < HDIM; d0 += 4) {
            const float4 kv = *(const float4*)(kp + d0);
#pragma unroll
            for (int i = 0; i < 32; ++i) {
                const float4 qv = *(const float4*)(Qbh + (size_t)(i0 + i) * HDIM + d0);
                acc[i] += qv.x * kv.x + qv.y * kv.y + qv.z * kv.z + qv.w * kv.w;
            }
        }
#pragma unroll
        for (int i = 0; i < 32; ++i) ssc[i][jj] = acc[i] * 0.125f;
    }
    __syncthreads();
    const int wv = tid >> 6, ln = tid & 63;
    float rs[8];
#pragma unroll
    for (int r = 0; r < 8; ++r) {
        const int i  = wv * 8 + r;
        const int qi = i0 + i;
        const int lo = max(0, qi - HALFW) - jmin;
        const int hi = min(SEQ - 1, qi + HALFW) - jmin;
        float m = -1e30f;
#pragma unroll
        for (int c = 0; c < 4; ++c) {
            const int j = ln + 64 * c;
            if (j >= lo && j <= hi) m = fmaxf(m, ssc[i][j]);
        }
#pragma unroll
        for (int off = 32; off > 0; off >>= 1) m = fmaxf(m, __shfl_xor(m, off));
        float sum = 0.f;
#pragma unroll
        for (int c = 0; c < 4; ++c) {
            const int j = ln + 64 * c;
            if (j < BWt) {
                float p = 0.f;
                if (j >= lo && j <= hi) p = __expf(ssc[i][j] - m);
                ssc[i][j] = p;
                sum += p;
            }
        }
#pragma unroll
        for (int off = 32; off > 0; off >>= 1) sum += __shfl_xor(sum, off);
        rs[r] = sum;
    }
    float oa[8];
#pragma unroll
    for (int r = 0; r < 8; ++r) oa[r] = 0.f;
    int jq = 0;
    for (; jq + 4 <= BWt; jq += 4) {
        const float v0 = Vbh[(size_t)(jmin + jq + 0) * HDIM + ln];
        const float v1 = Vbh[(size_t)(jmin + jq + 1) * HDIM + ln];
        const float v2 = Vbh[(size_t)(jmin + jq + 2) * HDIM + ln];
        const float v3 = Vbh[(size_t)(jmin + jq + 3) * HDIM + ln];
#pragma unroll
        for (int r = 0; r < 8; ++r) {
            const float4 p4 = *(const float4*)&ssc[wv * 8 + r][jq];
            oa[r] += p4.x * v0 + p4.y * v1 + p4.z * v2 + p4.w * v3;
        }
    }
    for (; jq < BWt; ++jq) {
        const float v0 = Vbh[(size_t)(jmin + jq) * HDIM + ln];
#pragma unroll
        for (int r = 0; r < 8; ++r) oa[r] += ssc[wv * 8 + r][jq] * v0;
    }
#pragma unroll
    for (int r = 0; r < 8; ++r) {
        const int i = i0 + wv * 8 + r;
        O[((size_t)b * SEQ + i) * DMODEL + h * HDIM + ln] = oa[r] / rs[r];
    }
}

// ---------------------------------------------------------------------------
extern "C" void kernel_launch(void* const* d_in, const int* in_sizes, int n_in,
                              void* d_out, int out_size, void* d_ws, size_t ws_size,
                              hipStream_t stream) {
    const float* x  = (const float*)d_in[0];
    const float* Wq = (const float*)d_in[1];
    const float* bq = (const float*)d_in[2];
    const float* Wk = (const float*)d_in[3];
    const float* bk = (const float*)d_in[4];
    const float* Wv = (const float*)d_in[5];
    const float* bv = (const float*)d_in[6];
    const float* Wo = (const float*)d_in[7];
    const float* bo = (const float*)d_in[8];

    float* out = (float*)d_out;

    const size_t REQUIRED = (size_t)80 * 1024 * 1024;
    if (ws_size >= REQUIRED) {
        const size_t M4 = 4194304;                       // 4M u16 = 8MB
        const size_t VT_ELEMS = (size_t)32 * HDIM * VTS; // 4,456,448 u16
        u16* Qb    = (u16*)d_ws;                         // bf16
        u16* Kb    = Qb + M4;                            // bf16
        u16* VTb   = Kb + M4;                            // bf16, padded rows
        u16* aoh   = VTb + VT_ELEMS;                     // fp16
        u16* xh    = aoh + M4;                           // fp16
        u16* wbase = xh + M4;                            // fp16: Wq,Wk,Wv,Wo (4x1M)

        hipMemsetAsync(VTb, 0, VT_ELEMS * sizeof(u16), stream);  // zero pad cols
        split5<<<dim3(4096, 5), 256, 0, stream>>>(x, Wq, Wk, Wv, Wo, xh, wbase);
        gemm_qkv<<<dim3(512, 3), 128, 0, stream>>>(xh, wbase, bq, bk, bv, Qb, Kb, VTb);
        attn_mfma<<<1024, 256, 0, stream>>>(Qb, Kb, VTb, aoh);
        gemm_out<<<512, 128, 0, stream>>>(aoh, wbase + 3145728, bo, out);
    } else {
        float* ws = (float*)d_ws;
        const size_t NELEM = (size_t)2 * SEQ * DMODEL;
        float* Qb = ws;
        float* Kb = ws + NELEM;
        float* Vb = ws + 2 * NELEM;
        float* AO = ws + 3 * NELEM;
        gemm_xwt<1><<<512, 256, 0, stream>>>(x, Wq, bq, Qb);
        gemm_xwt<1><<<512, 256, 0, stream>>>(x, Wk, bk, Kb);
        gemm_xwt<1><<<512, 256, 0, stream>>>(x, Wv, bv, Vb);
        attn_local_f32<<<2048, 256, 0, stream>>>(Qb, Kb, Vb, AO);
        gemm_xwt<0><<<512, 256, 0, stream>>>(AO, Wo, bo, out);
    }
}